// Round 1
// baseline (918.196 us; speedup 1.0000x reference)
//
#include <hip/hip_runtime.h>
#include <hip/hip_bf16.h>

#define BS 32
#define QL 16
#define KV 2048
#define NH 16
#define DK 128
#define DM 2048
#define MROWS (BS*QL)  // 512

#define SCALE 0.08838834764831845f  // 1/sqrt(128)
#define LOG2E 1.4426950408889634f

typedef __bf16 bf16x8 __attribute__((ext_vector_type(8)));
typedef float f32x4 __attribute__((ext_vector_type(4)));
typedef unsigned short us8 __attribute__((ext_vector_type(8)));

__device__ inline unsigned short f2bf(float f){
    unsigned u = __builtin_bit_cast(unsigned, f);
    u += 0x7fffu + ((u >> 16) & 1u);
    return (unsigned short)(u >> 16);
}

// C[m][n] = sum_k A[m][k] * W[n][k] + bias[n]
// A: 512 x 2048 (row major), W: 2048 x 2048 (row major, "B^T" form), C row stride 2048
// grid (M/64, N/64, nz), block 256 (4 waves). Wave w computes rows [w*16, w*16+16) x 64 cols.
__global__ __launch_bounds__(256) void gemm_bt(
    const float* __restrict__ A,
    const float* __restrict__ W0, const float* __restrict__ W1, const float* __restrict__ W2,
    const float* __restrict__ b0, const float* __restrict__ b1, const float* __restrict__ b2,
    float* __restrict__ C0, float* __restrict__ C1, float* __restrict__ C2)
{
    int z = blockIdx.z;
    const float* W    = (z==0)?W0:(z==1)?W1:W2;
    const float* bias = (z==0)?b0:(z==1)?b1:b2;
    float*       C    = (z==0)?C0:(z==1)?C1:C2;

    const int K = DM, N = DM;
    int mBase = blockIdx.x * 64, nBase = blockIdx.y * 64;

    __shared__ __align__(16) unsigned short As[64*40];  // pad 32->40 to spread banks
    __shared__ __align__(16) unsigned short Bs[64*40];

    int t = threadIdx.x;
    int wv = t >> 6, lane = t & 63;
    int row = t >> 2, seg = (t & 3) * 8;
    int g = lane >> 4, c = lane & 15;

    f32x4 acc[4] = {{0,0,0,0},{0,0,0,0},{0,0,0,0},{0,0,0,0}};

    for (int k0 = 0; k0 < K; k0 += 32) {
        __syncthreads();
        // stage A tile 64x32 (fp32 -> bf16)
        {
            const float* ap = A + (size_t)(mBase + row) * K + k0 + seg;
            float4 a0 = *(const float4*)ap, a1 = *(const float4*)(ap + 4);
            us8 av = { f2bf(a0.x), f2bf(a0.y), f2bf(a0.z), f2bf(a0.w),
                       f2bf(a1.x), f2bf(a1.y), f2bf(a1.z), f2bf(a1.w) };
            *(us8*)&As[row*40 + seg] = av;
        }
        // stage B tile 64x32 from W rows
        {
            const float* wp = W + (size_t)(nBase + row) * K + k0 + seg;
            float4 w0v = *(const float4*)wp, w1v = *(const float4*)(wp + 4);
            us8 wv8 = { f2bf(w0v.x), f2bf(w0v.y), f2bf(w0v.z), f2bf(w0v.w),
                        f2bf(w1v.x), f2bf(w1v.y), f2bf(w1v.z), f2bf(w1v.w) };
            *(us8*)&Bs[row*40 + seg] = wv8;
        }
        __syncthreads();

        bf16x8 af = __builtin_bit_cast(bf16x8, *(us8*)&As[(wv*16 + c)*40 + g*8]);
        #pragma unroll
        for (int j = 0; j < 4; j++) {
            bf16x8 bf = __builtin_bit_cast(bf16x8, *(us8*)&Bs[(j*16 + c)*40 + g*8]);
            acc[j] = __builtin_amdgcn_mfma_f32_16x16x32_bf16(af, bf, acc[j], 0, 0, 0);
        }
    }

    #pragma unroll
    for (int j = 0; j < 4; j++) {
        int n = nBase + j*16 + c;
        float bb = bias[n];
        #pragma unroll
        for (int r = 0; r < 4; r++) {
            int m = mBase + wv*16 + g*4 + r;
            C[(size_t)m * N + n] = acc[j][r] + bb;
        }
    }
}

// Copy caches to output, splicing the 16 new rows per batch from the projection ws.
__global__ void cache_copy(const float4* __restrict__ kin, const float4* __restrict__ vin,
                           const float4* __restrict__ kws, const float4* __restrict__ vws,
                           float4* __restrict__ kout, float4* __restrict__ vout)
{
    const unsigned NK4 = (unsigned)BS * KV * (DM/4);  // 33,554,432
    unsigned stride = gridDim.x * blockDim.x;
    for (unsigned i = blockIdx.x * blockDim.x + threadIdx.x; i < 2u*NK4; i += stride) {
        bool isV = i >= NK4;
        unsigned r = isV ? (i - NK4) : i;
        unsigned b  = r >> 20;            // 2048*512 = 2^20 float4 per batch
        unsigned r2 = r & 1048575u;
        unsigned s  = r2 >> 9;            // 512 float4 per row
        unsigned d4 = r2 & 511u;
        float4 val;
        if (s >= (unsigned)(KV - QL)) {
            const float4* ws = isV ? vws : kws;
            val = ws[((b*QL + (s - (KV - QL))) << 9) + d4];
        } else {
            val = (isV ? vin : kin)[r];
        }
        (isV ? vout : kout)[r] = val;
    }
}

// Flash-style attention. grid (NH, BS), block 512 (8 waves).
// Wave w handles KV rows [w*256, w*256+256) with online softmax; block combine in LDS.
__global__ __launch_bounds__(512) void attn_kernel(
    const float* __restrict__ qws, const float* __restrict__ kc, const float* __restrict__ vc,
    const int* __restrict__ mask, float* __restrict__ aout)
{
    int h = blockIdx.x, b = blockIdx.y;
    int t = threadIdx.x, wv = t >> 6, lane = t & 63;
    int g = lane >> 4, c = lane & 15;

    __shared__ __align__(16) unsigned short qlds[QL*DK];        // 4 KB
    __shared__ __align__(16) float red[8*QL*DK];                // 64 KB
    __shared__ float Ml[8*16], Ll[8*16];

    // stage q (scaled) as bf16
    {
        int idx = t * 4;
        int m = idx >> 7, d = idx & 127;
        const float* qp = qws + (size_t)(b*QL + m) * DM + h*DK + d;
        float4 qv = *(const float4*)qp;
        qlds[m*DK + d + 0] = f2bf(qv.x * SCALE);
        qlds[m*DK + d + 1] = f2bf(qv.y * SCALE);
        qlds[m*DK + d + 2] = f2bf(qv.z * SCALE);
        qlds[m*DK + d + 3] = f2bf(qv.w * SCALE);
    }
    __syncthreads();

    // hoist Q A-fragments (constant over kv loop)
    bf16x8 af[4];
    #pragma unroll
    for (int ks = 0; ks < 4; ks++)
        af[ks] = __builtin_bit_cast(bf16x8, *(us8*)&qlds[c*DK + ks*32 + g*8]);

    float Mx[4] = {-1e30f,-1e30f,-1e30f,-1e30f};
    float Ls[4] = {0.f,0.f,0.f,0.f};
    float O[4][8];
    #pragma unroll
    for (int r = 0; r < 4; r++)
        #pragma unroll
        for (int dd = 0; dd < 8; dd++) O[r][dd] = 0.f;

    int nStart = wv * 256;
    for (int nt = 0; nt < 16; nt++) {
        int n0 = nStart + nt * 16;
        // QK^T for a 16x16 score tile: B-frags straight from updated K cache (fp32->bf16)
        f32x4 sc = {0,0,0,0};
        const float* kp = kc + (size_t)(b*KV + n0 + c) * DM + h*DK + g*8;
        #pragma unroll
        for (int ks = 0; ks < 4; ks++) {
            float4 k0v = *(const float4*)(kp + ks*32);
            float4 k1v = *(const float4*)(kp + ks*32 + 4);
            us8 kv8 = { f2bf(k0v.x), f2bf(k0v.y), f2bf(k0v.z), f2bf(k0v.w),
                        f2bf(k1v.x), f2bf(k1v.y), f2bf(k1v.z), f2bf(k1v.w) };
            sc = __builtin_amdgcn_mfma_f32_16x16x32_bf16(af[ks], __builtin_bit_cast(bf16x8, kv8), sc, 0, 0, 0);
        }
        // mask (reference semantics; input is all-ones)
        #pragma unroll
        for (int r = 0; r < 4; r++) {
            int m = g*4 + r;
            int mk = mask[(size_t)(b*QL + m) * KV + n0 + c];
            if (mk == 0) sc[r] = -1e9f;
        }
        // online softmax (row = over n; n lives in the low-4 lane bits)
        float p[4], al[4];
        #pragma unroll
        for (int r = 0; r < 4; r++) {
            float rm = sc[r];
            #pragma unroll
            for (int mm = 1; mm < 16; mm <<= 1) rm = fmaxf(rm, __shfl_xor(rm, mm));
            float nM = fmaxf(Mx[r], rm);
            al[r] = exp2f((Mx[r] - nM) * LOG2E);
            p[r]  = exp2f((sc[r] - nM) * LOG2E);
            float rs = p[r];
            #pragma unroll
            for (int mm = 1; mm < 16; mm <<= 1) rs += __shfl_xor(rs, mm);
            Ls[r] = Ls[r] * al[r] + rs;
            Mx[r] = nM;
            #pragma unroll
            for (int dd = 0; dd < 8; dd++) O[r][dd] *= al[r];
        }
        // PV: fp32 VALU; lane owns d-chunk c*8..c*8+8 for its 4 m rows
        const float* vp = vc + (size_t)(b*KV + n0) * DM + h*DK + c*8;
        #pragma unroll
        for (int n = 0; n < 16; n++) {
            float4 v0 = *(const float4*)(vp + (size_t)n*DM);
            float4 v1 = *(const float4*)(vp + (size_t)n*DM + 4);
            float vvv[8] = {v0.x,v0.y,v0.z,v0.w,v1.x,v1.y,v1.z,v1.w};
            #pragma unroll
            for (int r = 0; r < 4; r++) {
                float pb = __shfl(p[r], (lane & 48) + n);
                #pragma unroll
                for (int dd = 0; dd < 8; dd++) O[r][dd] += pb * vvv[dd];
            }
        }
    }

    // per-wave partials -> LDS
    if (c == 0) {
        #pragma unroll
        for (int r = 0; r < 4; r++) {
            Ml[wv*16 + g*4 + r] = Mx[r];
            Ll[wv*16 + g*4 + r] = Ls[r];
        }
    }
    #pragma unroll
    for (int r = 0; r < 4; r++) {
        float4 o0 = {O[r][0],O[r][1],O[r][2],O[r][3]};
        float4 o1 = {O[r][4],O[r][5],O[r][6],O[r][7]};
        *(float4*)&red[wv*QL*DK + (g*4+r)*DK + c*8]     = o0;
        *(float4*)&red[wv*QL*DK + (g*4+r)*DK + c*8 + 4] = o1;
    }
    __syncthreads();

    // combine 8 wave-partials; each thread finalizes 4 output elements
    {
        int idx = t * 4;
        int m = idx >> 7, d = idx & 127;
        float Mg = -1e30f;
        #pragma unroll
        for (int w = 0; w < 8; w++) Mg = fmaxf(Mg, Ml[w*16 + m]);
        float L = 0.f, o0 = 0.f, o1 = 0.f, o2 = 0.f, o3 = 0.f;
        #pragma unroll
        for (int w = 0; w < 8; w++) {
            float scl = exp2f((Ml[w*16 + m] - Mg) * LOG2E);
            L += Ll[w*16 + m] * scl;
            const float* rp = &red[w*QL*DK + m*DK + d];
            o0 += rp[0]*scl; o1 += rp[1]*scl; o2 += rp[2]*scl; o3 += rp[3]*scl;
        }
        float inv = 1.0f / L;
        float4 ov = {o0*inv, o1*inv, o2*inv, o3*inv};
        *(float4*)&aout[(size_t)(b*QL + m) * DM + h*DK + d] = ov;
    }
}

extern "C" void kernel_launch(void* const* d_in, const int* in_sizes, int n_in,
                              void* d_out, int out_size, void* d_ws, size_t ws_size,
                              hipStream_t stream)
{
    (void)in_sizes; (void)n_in; (void)out_size; (void)ws_size;

    const float* x      = (const float*)d_in[0];
    const float* kcache = (const float*)d_in[1];
    const float* vcache = (const float*)d_in[2];
    const int*   mask   = (const int*)  d_in[3];
    const float* Wq     = (const float*)d_in[4];
    const float* bq     = (const float*)d_in[5];
    const float* Wk     = (const float*)d_in[6];
    const float* bk     = (const float*)d_in[7];
    const float* Wv     = (const float*)d_in[8];
    const float* bv     = (const float*)d_in[9];
    const float* Wo     = (const float*)d_in[10];
    const float* bo     = (const float*)d_in[11];

    float* out  = (float*)d_out;
    float* kout = out  + (size_t)MROWS * DM;      // 1,048,576 floats in
    float* vout = kout + (size_t)BS * KV * DM;    // +134,217,728

    float* qws = (float*)d_ws;
    float* kws = qws + (size_t)MROWS * DM;
    float* vws = kws + (size_t)MROWS * DM;
    float* aws = vws + (size_t)MROWS * DM;        // 16 MB total ws use

    // 1) QKV projections (one launch, z = matrix)
    dim3 gq(MROWS/64, DM/64, 3);
    gemm_bt<<<gq, 256, 0, stream>>>(x, Wq, Wk, Wv, bq, bk, bv, qws, kws, vws);

    // 2) cache copy + splice of new rows
    cache_copy<<<2048, 256, 0, stream>>>((const float4*)kcache, (const float4*)vcache,
                                         (const float4*)kws, (const float4*)vws,
                                         (float4*)kout, (float4*)vout);

    // 3) attention over updated caches (read from d_out regions)
    dim3 ga(NH, BS, 1);
    attn_kernel<<<ga, 512, 0, stream>>>(qws, kout, vout, mask, aws);

    // 4) output projection
    dim3 go(MROWS/64, DM/64, 1);
    gemm_bt<<<go, 256, 0, stream>>>(aws, Wo, Wo, Wo, bo, bo, bo, out, out, out);
}

// Round 2
// 824.761 us; speedup vs baseline: 1.1133x; 1.1133x over previous
//
#include <hip/hip_runtime.h>
#include <hip/hip_bf16.h>

#define BS 32
#define QL 16
#define KV 2048
#define NH 16
#define DK 128
#define DM 2048
#define MROWS (BS*QL)  // 512
#define CHUNKS 8
#define CROWS 256      // rows per chunk

#define SCALE 0.08838834764831845f  // 1/sqrt(128)
#define LOG2E 1.4426950408889634f

typedef __bf16 bf16x8 __attribute__((ext_vector_type(8)));
typedef float f32x4 __attribute__((ext_vector_type(4)));
typedef unsigned short us8 __attribute__((ext_vector_type(8)));

__device__ inline unsigned short f2bf(float f){
    unsigned u = __builtin_bit_cast(unsigned, f);
    u += 0x7fffu + ((u >> 16) & 1u);
    return (unsigned short)(u >> 16);
}
__device__ inline float bf2f(unsigned short u){
    unsigned x = ((unsigned)u) << 16;
    return __builtin_bit_cast(float, x);
}

// C[m][n] = sum_k A[m][k] * W[n][k] + bias[n]
// spliceMask bit z: output row m goes to cache row (m>>4)*KV + (KV-QL) + (m&15)
__global__ __launch_bounds__(256) void gemm_bt(
    const float* __restrict__ A,
    const float* __restrict__ W0, const float* __restrict__ W1, const float* __restrict__ W2,
    const float* __restrict__ b0, const float* __restrict__ b1, const float* __restrict__ b2,
    float* __restrict__ C0, float* __restrict__ C1, float* __restrict__ C2,
    int spliceMask)
{
    int z = blockIdx.z;
    const float* W    = (z==0)?W0:(z==1)?W1:W2;
    const float* bias = (z==0)?b0:(z==1)?b1:b2;
    float*       C    = (z==0)?C0:(z==1)?C1:C2;
    int spl = (spliceMask >> z) & 1;

    const int K = DM, N = DM;
    int mBase = blockIdx.x * 64, nBase = blockIdx.y * 64;

    __shared__ __align__(16) unsigned short As[64*40];
    __shared__ __align__(16) unsigned short Bs[64*40];

    int t = threadIdx.x;
    int wv = t >> 6, lane = t & 63;
    int row = t >> 2, seg = (t & 3) * 8;
    int g = lane >> 4, c = lane & 15;

    f32x4 acc[4] = {{0,0,0,0},{0,0,0,0},{0,0,0,0},{0,0,0,0}};

    for (int k0 = 0; k0 < K; k0 += 32) {
        __syncthreads();
        {
            const float* ap = A + (size_t)(mBase + row) * K + k0 + seg;
            float4 a0 = *(const float4*)ap, a1 = *(const float4*)(ap + 4);
            us8 av = { f2bf(a0.x), f2bf(a0.y), f2bf(a0.z), f2bf(a0.w),
                       f2bf(a1.x), f2bf(a1.y), f2bf(a1.z), f2bf(a1.w) };
            *(us8*)&As[row*40 + seg] = av;
        }
        {
            const float* wp = W + (size_t)(nBase + row) * K + k0 + seg;
            float4 w0v = *(const float4*)wp, w1v = *(const float4*)(wp + 4);
            us8 wv8 = { f2bf(w0v.x), f2bf(w0v.y), f2bf(w0v.z), f2bf(w0v.w),
                        f2bf(w1v.x), f2bf(w1v.y), f2bf(w1v.z), f2bf(w1v.w) };
            *(us8*)&Bs[row*40 + seg] = wv8;
        }
        __syncthreads();

        bf16x8 af = __builtin_bit_cast(bf16x8, *(us8*)&As[(wv*16 + c)*40 + g*8]);
        #pragma unroll
        for (int j = 0; j < 4; j++) {
            bf16x8 bf = __builtin_bit_cast(bf16x8, *(us8*)&Bs[(j*16 + c)*40 + g*8]);
            acc[j] = __builtin_amdgcn_mfma_f32_16x16x32_bf16(af, bf, acc[j], 0, 0, 0);
        }
    }

    #pragma unroll
    for (int j = 0; j < 4; j++) {
        int n = nBase + j*16 + c;
        float bb = bias[n];
        #pragma unroll
        for (int r = 0; r < 4; r++) {
            int m = mBase + wv*16 + g*4 + r;
            size_t rowoff = spl ? ((size_t)(m >> 4) * KV + (KV - QL) + (m & 15)) * (size_t)N
                                : (size_t)m * (size_t)N;
            C[rowoff + n] = acc[j][r] + bb;
        }
    }
}

// Fused cache-copy + flash-attention partials.
// grid (CHUNKS, BS), block 512 (8 waves). Wave w handles heads {w, w+8} over the
// chunk's 256 rows. Copy streams kcache/vcache -> kout/vout for the same rows;
// attention re-reads the source rows (L2-hot). Rows >= KV-QL were already written
// to kout/vout by gemm_bt (splice), so copy skips them and attn reads kout/vout.
__global__ __launch_bounds__(512) void fused_copy_attn(
    const float* __restrict__ qws,
    const float* __restrict__ kcache, const float* __restrict__ vcache,
    const int* __restrict__ mask,
    float* __restrict__ kout, float* __restrict__ vout,
    float* __restrict__ pM, float* __restrict__ pL, __hip_bfloat16* __restrict__ pO)
{
    int chunk = blockIdx.x, b = blockIdx.y;
    int t = threadIdx.x, wv = t >> 6, lane = t & 63;
    int g = lane >> 4, c = lane & 15;
    const int rowBase = chunk * CROWS;

    __shared__ int mlds[QL * CROWS];  // 16 KB

    {
        const int* mp = mask + (size_t)b * QL * KV + rowBase;
        for (int i = t; i < QL * CROWS; i += 512)
            mlds[i] = mp[(size_t)(i >> 8) * KV + (i & 255)];
    }
    __syncthreads();

    // Q fragments (scaled, bf16) for this wave's two heads
    bf16x8 af[2][4];
    #pragma unroll
    for (int hh = 0; hh < 2; hh++) {
        int h = wv + hh * 8;
        const float* qp = qws + (size_t)(b * QL + c) * DM + h * DK + g * 8;
        #pragma unroll
        for (int ks = 0; ks < 4; ks++) {
            float4 q0 = *(const float4*)(qp + ks * 32);
            float4 q1 = *(const float4*)(qp + ks * 32 + 4);
            us8 qv = { f2bf(q0.x*SCALE), f2bf(q0.y*SCALE), f2bf(q0.z*SCALE), f2bf(q0.w*SCALE),
                       f2bf(q1.x*SCALE), f2bf(q1.y*SCALE), f2bf(q1.z*SCALE), f2bf(q1.w*SCALE) };
            af[hh][ks] = __builtin_bit_cast(bf16x8, qv);
        }
    }

    float Mx[2][4], Ls[2][4], O[2][4][8];
    #pragma unroll
    for (int hh = 0; hh < 2; hh++)
        #pragma unroll
        for (int r = 0; r < 4; r++) {
            Mx[hh][r] = -1e30f; Ls[hh][r] = 0.f;
            #pragma unroll
            for (int d = 0; d < 8; d++) O[hh][r][d] = 0.f;
        }

    const size_t bKV = (size_t)b * KV;

    for (int nt = 0; nt < 16; nt++) {
        int n0 = rowBase + nt * 16;

        // ---- copy K rows [n0, n0+16) (skip spliced tail rows) ----
        #pragma unroll 4
        for (int i = 0; i < 16; i++) {
            int row = n0 + i;
            if (row < KV - QL) {
                const float4* s4 = (const float4*)(kcache + (bKV + row) * DM);
                float4* d4 = (float4*)(kout + (bKV + row) * DM);
                d4[t] = s4[t];
            }
        }

        // ---- QK^T (B-fragments straight from source rows, L2-hot) ----
        int krow = n0 + c;
        const float* kp = (krow >= KV - QL) ? (kout + (bKV + krow) * DM)
                                            : (kcache + (bKV + krow) * DM);
        float p[2][4];
        #pragma unroll
        for (int hh = 0; hh < 2; hh++) {
            const float* kph = kp + (wv + hh * 8) * DK + g * 8;
            f32x4 sc = {0, 0, 0, 0};
            #pragma unroll
            for (int ks = 0; ks < 4; ks++) {
                float4 k0 = *(const float4*)(kph + ks * 32);
                float4 k1 = *(const float4*)(kph + ks * 32 + 4);
                us8 kv8 = { f2bf(k0.x), f2bf(k0.y), f2bf(k0.z), f2bf(k0.w),
                            f2bf(k1.x), f2bf(k1.y), f2bf(k1.z), f2bf(k1.w) };
                sc = __builtin_amdgcn_mfma_f32_16x16x32_bf16(af[hh][ks],
                        __builtin_bit_cast(bf16x8, kv8), sc, 0, 0, 0);
            }
            #pragma unroll
            for (int r = 0; r < 4; r++)
                if (mlds[(g * 4 + r) * CROWS + nt * 16 + c] == 0) sc[r] = -1e9f;
            #pragma unroll
            for (int r = 0; r < 4; r++) {
                float rm = sc[r];
                #pragma unroll
                for (int mm = 1; mm < 16; mm <<= 1) rm = fmaxf(rm, __shfl_xor(rm, mm));
                float nM = fmaxf(Mx[hh][r], rm);
                float al = exp2f((Mx[hh][r] - nM) * LOG2E);
                float pp = exp2f((sc[r] - nM) * LOG2E);
                float rs = pp;
                #pragma unroll
                for (int mm = 1; mm < 16; mm <<= 1) rs += __shfl_xor(rs, mm);
                Ls[hh][r] = Ls[hh][r] * al + rs;
                Mx[hh][r] = nM;
                p[hh][r] = pp;
                #pragma unroll
                for (int d = 0; d < 8; d++) O[hh][r][d] *= al;
            }
        }

        // ---- copy V rows ----
        #pragma unroll 4
        for (int i = 0; i < 16; i++) {
            int row = n0 + i;
            if (row < KV - QL) {
                const float4* s4 = (const float4*)(vcache + (bKV + row) * DM);
                float4* d4 = (float4*)(vout + (bKV + row) * DM);
                d4[t] = s4[t];
            }
        }

        // ---- PV (source rows, L2-hot) ----
        #pragma unroll
        for (int n = 0; n < 16; n++) {
            int row = n0 + n;
            const float* vrow = (row >= KV - QL) ? (vout + (bKV + row) * DM)
                                                 : (vcache + (bKV + row) * DM);
            #pragma unroll
            for (int hh = 0; hh < 2; hh++) {
                const float* vp = vrow + (wv + hh * 8) * DK + c * 8;
                float4 v0 = *(const float4*)vp;
                float4 v1 = *(const float4*)(vp + 4);
                #pragma unroll
                for (int r = 0; r < 4; r++) {
                    float pb = __shfl(p[hh][r], (lane & 48) + n);
                    O[hh][r][0] += pb * v0.x; O[hh][r][1] += pb * v0.y;
                    O[hh][r][2] += pb * v0.z; O[hh][r][3] += pb * v0.w;
                    O[hh][r][4] += pb * v1.x; O[hh][r][5] += pb * v1.y;
                    O[hh][r][6] += pb * v1.z; O[hh][r][7] += pb * v1.w;
                }
            }
        }
    }

    // ---- write flash partials ----
    #pragma unroll
    for (int hh = 0; hh < 2; hh++) {
        int h = wv + hh * 8;
        size_t bh = (size_t)b * NH + h;
        #pragma unroll
        for (int r = 0; r < 4; r++) {
            int q = g * 4 + r;
            if (c == 0) {
                pM[(bh * QL + q) * CHUNKS + chunk] = Mx[hh][r];
                pL[(bh * QL + q) * CHUNKS + chunk] = Ls[hh][r];
            }
            us8 ov = { f2bf(O[hh][r][0]), f2bf(O[hh][r][1]), f2bf(O[hh][r][2]), f2bf(O[hh][r][3]),
                       f2bf(O[hh][r][4]), f2bf(O[hh][r][5]), f2bf(O[hh][r][6]), f2bf(O[hh][r][7]) };
            *(us8*)(void*)(pO + ((bh * CHUNKS + chunk) * QL + q) * DK + c * 8) = ov;
        }
    }
}

// Combine chunk partials. grid (NH, BS), 256 threads: thread -> (q, 8-wide d chunk)
__global__ __launch_bounds__(256) void attn_combine(
    const float* __restrict__ pM, const float* __restrict__ pL,
    const __hip_bfloat16* __restrict__ pO, float* __restrict__ aws)
{
    int h = blockIdx.x, b = blockIdx.y;
    int t = threadIdx.x;
    int q = t >> 4, dc = (t & 15) * 8;
    size_t bh = (size_t)b * NH + h;

    float m[CHUNKS], l[CHUNKS];
    #pragma unroll
    for (int ch = 0; ch < CHUNKS; ch++) {
        m[ch] = pM[(bh * QL + q) * CHUNKS + ch];
        l[ch] = pL[(bh * QL + q) * CHUNKS + ch];
    }
    float Mg = m[0];
    #pragma unroll
    for (int ch = 1; ch < CHUNKS; ch++) Mg = fmaxf(Mg, m[ch]);
    float L = 0.f, o[8] = {0,0,0,0,0,0,0,0};
    #pragma unroll
    for (int ch = 0; ch < CHUNKS; ch++) {
        float scl = exp2f((m[ch] - Mg) * LOG2E);
        L += l[ch] * scl;
        us8 ov = *(const us8*)(const void*)(pO + ((bh * CHUNKS + ch) * QL + q) * DK + dc);
        #pragma unroll
        for (int d = 0; d < 8; d++) o[d] += bf2f(ov[d]) * scl;
    }
    float inv = 1.0f / L;
    float* outp = aws + (size_t)(b * QL + q) * DM + h * DK + dc;
    float4 o0 = {o[0]*inv, o[1]*inv, o[2]*inv, o[3]*inv};
    float4 o1 = {o[4]*inv, o[5]*inv, o[6]*inv, o[7]*inv};
    *(float4*)outp = o0;
    *(float4*)(outp + 4) = o1;
}

extern "C" void kernel_launch(void* const* d_in, const int* in_sizes, int n_in,
                              void* d_out, int out_size, void* d_ws, size_t ws_size,
                              hipStream_t stream)
{
    (void)in_sizes; (void)n_in; (void)out_size; (void)ws_size;

    const float* x      = (const float*)d_in[0];
    const float* kcache = (const float*)d_in[1];
    const float* vcache = (const float*)d_in[2];
    const int*   mask   = (const int*)  d_in[3];
    const float* Wq     = (const float*)d_in[4];
    const float* bq     = (const float*)d_in[5];
    const float* Wk     = (const float*)d_in[6];
    const float* bk     = (const float*)d_in[7];
    const float* Wv     = (const float*)d_in[8];
    const float* bv     = (const float*)d_in[9];
    const float* Wo     = (const float*)d_in[10];
    const float* bo     = (const float*)d_in[11];

    float* out  = (float*)d_out;
    float* kout = out  + (size_t)MROWS * DM;
    float* vout = kout + (size_t)BS * KV * DM;

    float* qws = (float*)d_ws;                         // 1,048,576 f
    float* aws = qws + (size_t)MROWS * DM;             // 1,048,576 f
    float* pM  = aws + (size_t)MROWS * DM;             // 65,536 f
    float* pL  = pM + (size_t)BS * NH * QL * CHUNKS;   // 65,536 f
    __hip_bfloat16* pO = (__hip_bfloat16*)(pL + (size_t)BS * NH * QL * CHUNKS);

    // 1) QKV projections; K/V rows splice directly into cache outputs
    dim3 gq(MROWS/64, DM/64, 3);
    gemm_bt<<<gq, 256, 0, stream>>>(x, Wq, Wk, Wv, bq, bk, bv, qws, kout, vout, 0b110);

    // 2) fused cache copy + flash attention partials
    dim3 gf(CHUNKS, BS, 1);
    fused_copy_attn<<<gf, 512, 0, stream>>>(qws, kcache, vcache, mask,
                                            kout, vout, pM, pL, pO);

    // 3) combine partials
    dim3 gc(NH, BS, 1);
    attn_combine<<<gc, 256, 0, stream>>>(pM, pL, pO, aws);

    // 4) output projection
    dim3 go(MROWS/64, DM/64, 1);
    gemm_bt<<<go, 256, 0, stream>>>(aws, Wo, Wo, Wo, bo, bo, bo, out, out, out, 0);
}

// Round 5
// 635.849 us; speedup vs baseline: 1.4440x; 1.2971x over previous
//
#include <hip/hip_runtime.h>
#include <hip/hip_bf16.h>

#define BS 32
#define QL 16
#define KV 2048
#define NH 16
#define DK 128
#define DM 2048
#define MROWS (BS*QL)   // 512
#define KCA 4           // A k-chunks
#define AROWS (KV/KCA)  // 512
#define KCB 2           // B k-chunks
#define BROWS (KV/KCB)  // 1024
#define SPLICE (KV-QL)  // 2032

#define SCALE 0.08838834764831845f  // 1/sqrt(128)
#define LOG2E 1.4426950408889634f

typedef __bf16 bf16x8 __attribute__((ext_vector_type(8)));
typedef float f32x4 __attribute__((ext_vector_type(4)));
typedef unsigned short us8 __attribute__((ext_vector_type(8)));
typedef unsigned short us4 __attribute__((ext_vector_type(4)));

__device__ inline unsigned short f2bf(float f){
    unsigned u = __builtin_bit_cast(unsigned, f);
    u += 0x7fffu + ((u >> 16) & 1u);
    return (unsigned short)(u >> 16);
}
__device__ inline float bf2f(unsigned short u){
    unsigned x = ((unsigned)u) << 16;
    return __builtin_bit_cast(float, x);
}

// C[m][n] = sum_k (A[m][k](+A2[m][k])) * W[n][k] + bias[n]
__global__ __launch_bounds__(256) void gemm_bt(
    const float* __restrict__ A, const float* __restrict__ A2,
    const float* __restrict__ W0, const float* __restrict__ W1, const float* __restrict__ W2,
    const float* __restrict__ b0, const float* __restrict__ b1, const float* __restrict__ b2,
    float* __restrict__ C0, float* __restrict__ C1, float* __restrict__ C2,
    int spliceMask)
{
    int z = blockIdx.z;
    const float* W    = (z==0)?W0:(z==1)?W1:W2;
    const float* bias = (z==0)?b0:(z==1)?b1:b2;
    float*       C    = (z==0)?C0:(z==1)?C1:C2;
    int spl = (spliceMask >> z) & 1;

    const int K = DM, N = DM;
    int mBase = blockIdx.x * 64, nBase = blockIdx.y * 64;

    __shared__ __align__(16) unsigned short As[64*40];
    __shared__ __align__(16) unsigned short Bs[64*40];

    int t = threadIdx.x;
    int wv = t >> 6, lane = t & 63;
    int row = t >> 2, seg = (t & 3) * 8;
    int g = lane >> 4, c = lane & 15;

    f32x4 acc[4] = {{0,0,0,0},{0,0,0,0},{0,0,0,0},{0,0,0,0}};

    for (int k0 = 0; k0 < K; k0 += 32) {
        __syncthreads();
        {
            const float* ap = A + (size_t)(mBase + row) * K + k0 + seg;
            float4 a0 = *(const float4*)ap, a1 = *(const float4*)(ap + 4);
            if (A2) {
                const float* ap2 = A2 + (size_t)(mBase + row) * K + k0 + seg;
                float4 c0 = *(const float4*)ap2, c1 = *(const float4*)(ap2 + 4);
                a0.x+=c0.x; a0.y+=c0.y; a0.z+=c0.z; a0.w+=c0.w;
                a1.x+=c1.x; a1.y+=c1.y; a1.z+=c1.z; a1.w+=c1.w;
            }
            us8 av = { f2bf(a0.x), f2bf(a0.y), f2bf(a0.z), f2bf(a0.w),
                       f2bf(a1.x), f2bf(a1.y), f2bf(a1.z), f2bf(a1.w) };
            *(us8*)&As[row*40 + seg] = av;
        }
        {
            const float* wp = W + (size_t)(nBase + row) * K + k0 + seg;
            float4 w0v = *(const float4*)wp, w1v = *(const float4*)(wp + 4);
            us8 wv8 = { f2bf(w0v.x), f2bf(w0v.y), f2bf(w0v.z), f2bf(w0v.w),
                        f2bf(w1v.x), f2bf(w1v.y), f2bf(w1v.z), f2bf(w1v.w) };
            *(us8*)&Bs[row*40 + seg] = wv8;
        }
        __syncthreads();

        bf16x8 af = __builtin_bit_cast(bf16x8, *(us8*)&As[(wv*16 + c)*40 + g*8]);
        #pragma unroll
        for (int j = 0; j < 4; j++) {
            bf16x8 bf = __builtin_bit_cast(bf16x8, *(us8*)&Bs[(j*16 + c)*40 + g*8]);
            acc[j] = __builtin_amdgcn_mfma_f32_16x16x32_bf16(af, bf, acc[j], 0, 0, 0);
        }
    }

    #pragma unroll
    for (int j = 0; j < 4; j++) {
        int n = nBase + j*16 + c;
        float bb = bias[n];
        #pragma unroll
        for (int r = 0; r < 4; r++) {
            int m = mBase + wv*16 + g*4 + r;
            size_t rowoff = spl ? ((size_t)(m >> 4) * KV + SPLICE + (m & 15)) * (size_t)N
                                : (size_t)m * (size_t)N;
            C[rowoff + n] = acc[j][r] + bb;
        }
    }
}

// A: K-copy fused with QK^T. The copy loads ARE the MFMA B-fragments.
// grid (NH, BS, KCA), 256 threads (4 waves, 8 tiles of 16 rows each).
// Writes masked bf16 scores S[b][h][k][q] and per-chunk softmax stats.
__global__ __launch_bounds__(256) void kcopy_scores(
    const float* __restrict__ qws, const float* __restrict__ kcache,
    const int* __restrict__ mask,
    float* __restrict__ kout, __hip_bfloat16* __restrict__ Sbuf,
    float* __restrict__ statsM, float* __restrict__ statsL)
{
    int h = blockIdx.x, b = blockIdx.y, kc = blockIdx.z;
    int t = threadIdx.x, wv = t >> 6, lane = t & 63;
    int g = lane >> 4, c = lane & 15;
    size_t bKV = (size_t)b * KV;
    size_t bh  = (size_t)b * NH + h;
    unsigned short* S = (unsigned short*)Sbuf;

    __shared__ float smM[4][16], smL[4][16];

    // Q A-fragments for head h (scaled, bf16); constant over the loop
    bf16x8 af[4];
    {
        const float* qp = qws + (size_t)(b*QL + c) * DM + h*DK + g*8;
        #pragma unroll
        for (int ks = 0; ks < 4; ks++) {
            float4 q0 = *(const float4*)(qp + ks*32);
            float4 q1 = *(const float4*)(qp + ks*32 + 4);
            us8 qv = { f2bf(q0.x*SCALE), f2bf(q0.y*SCALE), f2bf(q0.z*SCALE), f2bf(q0.w*SCALE),
                       f2bf(q1.x*SCALE), f2bf(q1.y*SCALE), f2bf(q1.z*SCALE), f2bf(q1.w*SCALE) };
            af[ks] = __builtin_bit_cast(bf16x8, qv);
        }
    }

    float mloc[4] = {-1e30f,-1e30f,-1e30f,-1e30f};
    float lloc[4] = {0.f,0.f,0.f,0.f};

    for (int i = 0; i < 8; i++) {
        int n0 = kc*AROWS + (i*4 + wv)*16;
        int krow = n0 + c;
        bool spl = (n0 >= SPLICE);   // tile-uniform: only the last tile
        const float* src = (spl ? kout : kcache) + (bKV + krow)*DM + h*DK + g*8;

        float4 kvv[8];
        #pragma unroll
        for (int ks = 0; ks < 4; ks++) {
            kvv[2*ks]   = *(const float4*)(src + ks*32);
            kvv[2*ks+1] = *(const float4*)(src + ks*32 + 4);
        }
        if (!spl) {
            float* dst = kout + (bKV + krow)*DM + h*DK + g*8;
            #pragma unroll
            for (int ks = 0; ks < 4; ks++) {
                *(float4*)(dst + ks*32)     = kvv[2*ks];
                *(float4*)(dst + ks*32 + 4) = kvv[2*ks+1];
            }
        }
        f32x4 sc = {0,0,0,0};
        #pragma unroll
        for (int ks = 0; ks < 4; ks++) {
            float4 k0 = kvv[2*ks], k1 = kvv[2*ks+1];
            us8 kb = { f2bf(k0.x), f2bf(k0.y), f2bf(k0.z), f2bf(k0.w),
                       f2bf(k1.x), f2bf(k1.y), f2bf(k1.z), f2bf(k1.w) };
            sc = __builtin_amdgcn_mfma_f32_16x16x32_bf16(af[ks],
                    __builtin_bit_cast(bf16x8, kb), sc, 0, 0, 0);
        }
        // mask, round to bf16, online stats, store S (8B per lane)
        const int* mrow = mask + (size_t)b * QL * KV + krow;
        us4 sv;
        #pragma unroll
        for (int r = 0; r < 4; r++) {
            int q = g*4 + r;
            float s = sc[r];
            if (mrow[(size_t)q * KV] == 0) s = -1e9f;
            unsigned short u = f2bf(s);
            sv[r] = u;
            float sb = bf2f(u);
            float nm = fmaxf(mloc[r], sb);
            lloc[r] = lloc[r]*exp2f((mloc[r]-nm)*LOG2E) + exp2f((sb-nm)*LOG2E);
            mloc[r] = nm;
        }
        *(us4*)(void*)&S[(bh*KV + krow)*QL + g*4] = sv;
    }

    // reduce stats across the 16 c-lanes
    #pragma unroll
    for (int r = 0; r < 4; r++) {
        float m = mloc[r], l = lloc[r];
        #pragma unroll
        for (int mm = 1; mm < 16; mm <<= 1) {
            float mo = __shfl_xor(m, mm), lo = __shfl_xor(l, mm);
            float nm = fmaxf(m, mo);
            l = l*exp2f((m-nm)*LOG2E) + lo*exp2f((mo-nm)*LOG2E);
            m = nm;
        }
        if (c == 0) { smM[wv][g*4+r] = m; smL[wv][g*4+r] = l; }
    }
    __syncthreads();
    if (t < 16) {
        float M = -1e30f;
        #pragma unroll
        for (int w = 0; w < 4; w++) M = fmaxf(M, smM[w][t]);
        float L = 0.f;
        #pragma unroll
        for (int w = 0; w < 4; w++) L += smL[w][t]*exp2f((smM[w][t]-M)*LOG2E);
        statsM[(bh*KCA + kc)*QL + t] = M;
        statsL[(bh*KCA + kc)*QL + t] = L;
    }
}

// B: V-copy fused with PV. grid (NH*2, BS, KCB), 256 threads.
// Block owns a 64-dim half of head h over BROWS k-rows: copies V slice,
// stages V (bf16) + P (f32) in LDS, accumulates O, writes normalized O
// partials (partial buffers summed by the final GEMM's A-staging).
__global__ __launch_bounds__(256) void vcopy_pv(
    const float* __restrict__ vcache, const __hip_bfloat16* __restrict__ Sbuf,
    const float* __restrict__ statsM, const float* __restrict__ statsL,
    float* __restrict__ vout, float* __restrict__ awsP)
{
    int hd = blockIdx.x; int h = hd >> 1, half = hd & 1;
    int b = blockIdx.y, kc = blockIdx.z;
    int t = threadIdx.x;
    size_t bKV = (size_t)b * KV;
    size_t bh  = (size_t)b * NH + h;
    const unsigned short* S = (const unsigned short*)Sbuf;

    __shared__ float smM[16], smLinv[16];
    __shared__ __align__(16) unsigned short Vl[64*72];  // 64 rows x 64 dims, pad to 72
    __shared__ __align__(16) float Pl[16*68];           // 16 q x 64 k, pad to 68

    if (t < 16) {
        float M = -1e30f;
        #pragma unroll
        for (int c4 = 0; c4 < KCA; c4++)
            M = fmaxf(M, statsM[(bh*KCA + c4)*QL + t]);
        float L = 0.f;
        #pragma unroll
        for (int c4 = 0; c4 < KCA; c4++)
            L += statsL[(bh*KCA + c4)*QL + t]*exp2f((statsM[(bh*KCA + c4)*QL + t]-M)*LOG2E);
        smM[t] = M; smLinv[t] = 1.0f / L;
    }
    __syncthreads();

    int q = t >> 4, dc = t & 15;
    int srow = t >> 2;                 // staging row 0..63
    int vseg = (t & 3) * 16;           // 16-float staging segment within 64 dims
    int pq0  = (t & 3) * 4;            // staging q quarter

    float O[4] = {0.f,0.f,0.f,0.f};

    for (int kt = 0; kt < 16; kt++) {
        int k0 = kc*BROWS + kt*64;
        __syncthreads();
        // ---- stage P = exp(S - M) ----
        {
            int krow = k0 + srow;
            us4 sv = *(const us4*)(const void*)&S[(bh*KV + krow)*QL + pq0];
            #pragma unroll
            for (int j = 0; j < 4; j++)
                Pl[(pq0+j)*68 + srow] = exp2f((bf2f(sv[j]) - smM[pq0+j])*LOG2E);
        }
        // ---- stage V (copy + bf16 to LDS) ----
        {
            int vrow = k0 + srow;
            bool cpy = (vrow < SPLICE);
            const float* src = (cpy ? vcache : vout) + (bKV + vrow)*DM + h*DK + half*64 + vseg;
            float4 v0 = *(const float4*)(src);
            float4 v1 = *(const float4*)(src + 4);
            float4 v2 = *(const float4*)(src + 8);
            float4 v3 = *(const float4*)(src + 12);
            if (cpy) {
                float* dst = vout + (bKV + vrow)*DM + h*DK + half*64 + vseg;
                *(float4*)(dst)      = v0;
                *(float4*)(dst + 4)  = v1;
                *(float4*)(dst + 8)  = v2;
                *(float4*)(dst + 12) = v3;
            }
            us8 p0 = { f2bf(v0.x), f2bf(v0.y), f2bf(v0.z), f2bf(v0.w),
                       f2bf(v1.x), f2bf(v1.y), f2bf(v1.z), f2bf(v1.w) };
            us8 p1 = { f2bf(v2.x), f2bf(v2.y), f2bf(v2.z), f2bf(v2.w),
                       f2bf(v3.x), f2bf(v3.y), f2bf(v3.z), f2bf(v3.w) };
            *(us8*)&Vl[srow*72 + vseg]     = p0;
            *(us8*)&Vl[srow*72 + vseg + 8] = p1;
        }
        __syncthreads();
        // ---- O += P * V ----
        #pragma unroll
        for (int kk0 = 0; kk0 < 64; kk0 += 4) {
            float4 pv = *(const float4*)&Pl[q*68 + kk0];
            #pragma unroll
            for (int j = 0; j < 4; j++) {
                us4 vb = *(const us4*)(const void*)&Vl[(kk0+j)*72 + dc*4];
                float pj = pv[j];
                O[0] += pj*bf2f(vb[0]); O[1] += pj*bf2f(vb[1]);
                O[2] += pj*bf2f(vb[2]); O[3] += pj*bf2f(vb[3]);
            }
        }
    }

    float inv = smLinv[q];
    float* op = awsP + (size_t)kc * MROWS * DM
              + (size_t)(b*QL + q)*DM + h*DK + half*64 + dc*4;
    float4 ov = {O[0]*inv, O[1]*inv, O[2]*inv, O[3]*inv};
    *(float4*)op = ov;
}

extern "C" void kernel_launch(void* const* d_in, const int* in_sizes, int n_in,
                              void* d_out, int out_size, void* d_ws, size_t ws_size,
                              hipStream_t stream)
{
    (void)in_sizes; (void)n_in; (void)out_size; (void)ws_size;

    const float* x      = (const float*)d_in[0];
    const float* kcache = (const float*)d_in[1];
    const float* vcache = (const float*)d_in[2];
    const int*   mask   = (const int*)  d_in[3];
    const float* Wq     = (const float*)d_in[4];
    const float* bq     = (const float*)d_in[5];
    const float* Wk     = (const float*)d_in[6];
    const float* bk     = (const float*)d_in[7];
    const float* Wv     = (const float*)d_in[8];
    const float* bv     = (const float*)d_in[9];
    const float* Wo     = (const float*)d_in[10];
    const float* bo     = (const float*)d_in[11];

    float* out  = (float*)d_out;
    float* kout = out  + (size_t)MROWS * DM;
    float* vout = kout + (size_t)BS * KV * DM;

    float* qws    = (float*)d_ws;                         // 4 MB
    float* aws0   = qws  + (size_t)MROWS * DM;            // 4 MB (kc=0 partial)
    float* aws1   = aws0 + (size_t)MROWS * DM;            // 4 MB (kc=1 partial)
    float* statsM = aws1 + (size_t)MROWS * DM;            // 128 KB
    float* statsL = statsM + (size_t)BS * NH * KCA * QL;  // 128 KB
    __hip_bfloat16* Sbuf = (__hip_bfloat16*)(statsL + (size_t)BS * NH * KCA * QL); // 32 MB

    // 1) QKV projections; K/V rows splice directly into cache outputs
    dim3 gq(MROWS/64, DM/64, 3);
    gemm_bt<<<gq, 256, 0, stream>>>(x, nullptr, Wq, Wk, Wv, bq, bk, bv,
                                    qws, kout, vout, 0b110);

    // 2) K-copy + scores + stats
    dim3 ga(NH, BS, KCA);
    kcopy_scores<<<ga, 256, 0, stream>>>(qws, kcache, mask, kout, Sbuf, statsM, statsL);

    // 3) V-copy + PV partials (kc=0 -> aws0, kc=1 -> aws1 via in-kernel offset)
    dim3 gb(NH*2, BS, KCB);
    vcopy_pv<<<gb, 256, 0, stream>>>(vcache, Sbuf, statsM, statsL, vout, aws0);

    // 4) output projection, summing the two PV partial buffers
    dim3 go(MROWS/64, DM/64, 1);
    gemm_bt<<<go, 256, 0, stream>>>(aws0, aws1, Wo, Wo, Wo, bo, bo, bo,
                                    out, out, out, 0);
}